// Round 14
// baseline (622.548 us; speedup 1.0000x reference)
//
#include <hip/hip_runtime.h>
#include <cstdint>
#include <cstddef>

#define NPTS 262144
#define BLK 256
#define TGX 176
#define TGY 200
#define TGZ 1

#define G_TOPC 70400
#define G_MEDC 1126400
#define G_LOWC 4505600

#define SCAN_ITEMS 32
#define SCAN_CHUNK (BLK*SCAN_ITEMS)
// batched scan block counts / bsum offsets (disjoint: [0,9) [16,154) [160,710))
#define NB_T 9
#define NB_M 138
#define NB_L 550
#define BO_T 0
#define BO_M 16
#define BO_L 160
// vox13 block split
#define NBVT (G_TOPC/BLK)      // 275
#define NBVM (NPTS/BLK)        // 1024
#define NBVL (NPTS/BLK)        // 1024

#define Y2B2 (NPTS/64)         // 4096 blocks per scale (64-row MFMA tiles)
#define ST1BLKS 256            // fmom blocks per scale (1024 rows each)
// batched per-scale stage grids
#define NHT2 2200              // G_TOPC*8/BLK   (hsegT top, 8 ch/thread)
#define NHM2 4096              // NPTS*4/BLK     (hsegT med/low)
#define NJT2 4400              // G_TOPC*16/BLK  (hseg2 top, 8 ch/thread)
#define NJM2 8192              // NPTS*8/BLK     (hseg2 med/low)
#define NMG 4400               // G_TOPC*16/BLK  (merge, 16 thr/voxel)
#define FINB 32768             // NPTS*32/BLK    (fin)
#define NCL 275                // G_TOPC/BLK (ceil)

typedef __attribute__((ext_vector_type(8))) short bf16x8;
typedef __attribute__((ext_vector_type(4))) float f32x4;

// ---------------- per-scale parameter pack ----------------
struct SP {
  const float4* srt; const int* jr; const float4* vm;
  const float* W1; const float* W2;
  const float* g1; const float* b1; const float* g2; const float* b2;
  const int* cnt; const int* uniq; const int* woff; const int* U;
  unsigned short* segt;        // bf16, ROW-major [voxel][C1]
  float* part1; float* part2;
  float* coef1; float* coef2;
  unsigned short* Y2;          // bf16 storage
  float* hout;
  int C1; int segstride; int gx, gy, gz; float vx, vy, vz;
};

// ---------------- bf16 helpers ----------------
__device__ __forceinline__ unsigned short f2bf(float v) {
  unsigned u = __float_as_uint(v);
  u += 0x7FFFu + ((u >> 16) & 1u);      // round-to-nearest-even
  return (unsigned short)(u >> 16);
}
__device__ __forceinline__ float bf2f(unsigned short h) {
  return __uint_as_float((unsigned)h << 16);
}

// ---------------- voxel coord helpers ----------------
__device__ __forceinline__ void pcoords(float x, float y, float z,
    float vx, float vy, float vz, int gx, int gy, int gz,
    int& cx, int& cy, int& cz) {
  cx = (int)floorf((x - 0.0f)  / vx);
  cy = (int)floorf((y + 40.0f) / vy);
  cz = (int)floorf((z + 3.0f)  / vz);
  cx = min(max(cx, 0), gx - 1);
  cy = min(max(cy, 0), gy - 1);
  cz = min(max(cz, 0), gz - 1);
}

__device__ __forceinline__ int lin3(float b, float x, float y, float z,
    float vx, float vy, float vz, int gx, int gy, int gz) {
  int cx, cy, cz; pcoords(x, y, z, vx, vy, vz, gx, gy, gz, cx, cy, cz);
  return (((int)b * gz + cz) * gy + cy) * gx + cx;
}

// f-vector (10 features) — identical expression everywhere y1 is recomputed.
__device__ __forceinline__ void build_f(float4 p, float4 vm,
    float vx, float vy, float vz, int gx, int gy, int gz, float* f) {
  int cx, cy, cz; pcoords(p.x, p.y, p.z, vx, vy, vz, gx, gy, gz, cx, cy, cz);
  f[0] = p.x; f[1] = p.y; f[2] = p.z; f[3] = p.w;
  f[4] = p.x - vm.x;
  f[5] = p.y - vm.y;
  f[6] = p.z - vm.z;
  f[7] = p.x - (0.0f   + (cx + 0.5f)*vx);
  f[8] = p.y - (-40.0f + (cy + 0.5f)*vy);
  f[9] = p.z - (-3.0f  + (cz + 0.5f)*vz);
}

// ------- fused: dense count (3 scales) + W2 bf16 fragment pre-pack ----------
__global__ __launch_bounds__(BLK) void k_count3pack(const float* __restrict__ pts,
    int* __restrict__ ct, int* __restrict__ cm, int* __restrict__ cl,
    const float* __restrict__ W2t_, unsigned short* __restrict__ Bt,
    const float* __restrict__ W2m_, unsigned short* __restrict__ Bm,
    const float* __restrict__ W2l_, unsigned short* __restrict__ Bl) {
  int bid = blockIdx.x;
  if (bid < NPTS/BLK) {
    int i = bid * BLK + threadIdx.x;
    float b = pts[i*5+0], x = pts[i*5+1], y = pts[i*5+2], z = pts[i*5+3];
    atomicAdd(&ct[lin3(b,x,y,z, 0.4f,0.4f,4.0f, 176,200,1)], 1);
    atomicAdd(&cm[lin3(b,x,y,z, 0.2f,0.2f,2.0f, 352,400,2)], 1);
    atomicAdd(&cl[lin3(b,x,y,z, 0.1f,0.1f,1.0f, 704,800,4)], 1);
    return;
  }
  int pb = bid - NPTS/BLK;
  const float* W2; unsigned short* Bp; int C2, idx;
  if (pb < 64)      { W2 = W2t_; Bp = Bt; C2 = 128; idx = pb*BLK + threadIdx.x; }
  else if (pb < 80) { W2 = W2m_; Bp = Bm; C2 = 64;  idx = (pb-64)*BLK + threadIdx.x; }
  else              { W2 = W2l_; Bp = Bl; C2 = 64;  idx = (pb-80)*BLK + threadIdx.x; }
  if (idx >= C2*C2) return;            // K == C2 for all scales
  int NCF = C2/16;
  int per_kb = NCF*512;
  int kb = idx / per_kb, rem = idx % per_kb;
  int cf = rem / 512, r2 = rem % 512;
  int lane = r2 >> 3, j = r2 & 7;
  int k = kb*32 + (lane >> 4)*8 + j;
  int col = cf*16 + (lane & 15);
  Bp[idx] = f2bf(W2[(size_t)k*C2 + col]);
}

// ---------------- batched scans ----------------
__global__ __launch_bounds__(BLK) void k_scan1_all(const int* __restrict__ ct,
    const int* __restrict__ cm, const int* __restrict__ cl,
    int2* __restrict__ bsum) {
  int bid = blockIdx.x;
  const int* cnt; int G, bo, cb;
  if (bid < NB_T)            { cnt = ct; G = G_TOPC; bo = BO_T; cb = bid; }
  else if (bid < NB_T+NB_M)  { cnt = cm; G = G_MEDC; bo = BO_M; cb = bid - NB_T; }
  else                       { cnt = cl; G = G_LOWC; bo = BO_L; cb = bid - NB_T - NB_M; }
  int base = cb * SCAN_CHUNK + threadIdx.x * SCAN_ITEMS;
  int so = 0, sp = 0;
  #pragma unroll
  for (int k = 0; k < SCAN_ITEMS; k++) {
    int j = base + k;
    if (j < G) { int c = cnt[j]; if (c > 0) { so++; sp += c; } }
  }
  __shared__ int sho[BLK], shp[BLK];
  sho[threadIdx.x] = so; shp[threadIdx.x] = sp; __syncthreads();
  for (int off = BLK/2; off > 0; off >>= 1) {
    if (threadIdx.x < off) {
      sho[threadIdx.x] += sho[threadIdx.x + off];
      shp[threadIdx.x] += shp[threadIdx.x + off];
    }
    __syncthreads();
  }
  if (threadIdx.x == 0) { int2 v; v.x = sho[0]; v.y = shp[0]; bsum[bo + cb] = v; }
}

// ---- scan2: 3 independent wave-level shuffle scans (no __syncthreads) ------
__global__ __launch_bounds__(192) void k_scan2_all(int2* __restrict__ bsum,
    int* __restrict__ Ut, int* __restrict__ Um, int* __restrict__ Ul) {
  int wv = threadIdx.x >> 6;
  int lane = threadIdx.x & 63;
  int off, nb; int* U;
  if (wv == 0)      { off = BO_T; nb = NB_T; U = Ut; }
  else if (wv == 1) { off = BO_M; nb = NB_M; U = Um; }
  else              { off = BO_L; nb = NB_L; U = Ul; }
  const int IPL = 9;                       // 64*9 = 576 >= 550
  int eo[IPL], ep[IPL];
  int accO = 0, accP = 0;
  #pragma unroll
  for (int k = 0; k < IPL; k++) {
    int idx = lane*IPL + k;
    int2 t = {0, 0};
    if (idx < nb) t = bsum[off + idx];
    eo[k] = accO; ep[k] = accP;            // within-lane exclusive prefix
    accO += t.x; accP += t.y;
  }
  int xo = accO, xp = accP;
  #pragma unroll
  for (int d = 1; d < 64; d <<= 1) {
    int to = __shfl_up(xo, d);
    int tp = __shfl_up(xp, d);
    if (lane >= d) { xo += to; xp += tp; }
  }
  int baseO = xo - accO, baseP = xp - accP;
  #pragma unroll
  for (int k = 0; k < IPL; k++) {
    int idx = lane*IPL + k;
    if (idx < nb) { int2 e; e.x = baseO + eo[k]; e.y = baseP + ep[k]; bsum[off + idx] = e; }
  }
  int tot = __shfl(xo, 63);
  if (lane == 0) *U = tot;
}

__global__ __launch_bounds__(BLK) void k_scan3_all(const int* __restrict__ ct,
    const int* __restrict__ cm, const int* __restrict__ cl,
    const int2* __restrict__ bsum,
    int* __restrict__ rkt, int* __restrict__ rkm, int* __restrict__ rkl,
    int* __restrict__ uqt, int* __restrict__ uqm, int* __restrict__ uql,
    int* __restrict__ wot, int* __restrict__ wom, int* __restrict__ wol) {
  int bid = blockIdx.x;
  const int* cnt; int G, bo, cb; int *rank, *uniq, *woff;
  if (bid < NB_T)           { cnt=ct; G=G_TOPC; bo=BO_T; cb=bid;            rank=rkt; uniq=uqt; woff=wot; }
  else if (bid < NB_T+NB_M) { cnt=cm; G=G_MEDC; bo=BO_M; cb=bid-NB_T;       rank=rkm; uniq=uqm; woff=wom; }
  else                      { cnt=cl; G=G_LOWC; bo=BO_L; cb=bid-NB_T-NB_M;  rank=rkl; uniq=uql; woff=wol; }
  int base = cb * SCAN_CHUNK + threadIdx.x * SCAN_ITEMS;
  int so = 0, sp = 0;
  #pragma unroll
  for (int k = 0; k < SCAN_ITEMS; k++) {
    int j = base + k;
    if (j < G) { int c = cnt[j]; if (c > 0) { so++; sp += c; } }
  }
  __shared__ int sho[BLK], shp[BLK];
  sho[threadIdx.x] = so; shp[threadIdx.x] = sp; __syncthreads();
  for (int off = 1; off < BLK; off <<= 1) {
    int ao = (threadIdx.x >= off) ? sho[threadIdx.x - off] : 0;
    int ap = (threadIdx.x >= off) ? shp[threadIdx.x - off] : 0;
    __syncthreads();
    sho[threadIdx.x] += ao; shp[threadIdx.x] += ap;
    __syncthreads();
  }
  int2 bb = bsum[bo + cb];
  int ro = bb.x + sho[threadIdx.x] - so;
  int po = bb.y + shp[threadIdx.x] - sp;
  for (int k = 0; k < SCAN_ITEMS; k++) {
    int j = base + k;
    if (j < G) {
      int c = cnt[j];
      if (c > 0) { rank[j] = ro; uniq[ro] = j; woff[ro] = po; ro++; po += c; }
    }
  }
}

// ------- fused: counting-sort scatter (3 scales) + parent child-lists -------
__global__ __launch_bounds__(BLK) void k_scatclist(const float* __restrict__ pts,
    const int* __restrict__ rkt, int* __restrict__ wot, float4* __restrict__ st, int* __restrict__ jt,
    const int* __restrict__ rkm, int* __restrict__ wom, float4* __restrict__ sm, int* __restrict__ jm,
    const int* __restrict__ rkl, int* __restrict__ wol, float4* __restrict__ sl, int* __restrict__ jl,
    const int* __restrict__ tuniq, const int* __restrict__ Utp,
    const int* __restrict__ cnt_m, const int* __restrict__ rank_m,
    int* __restrict__ clist_m, int* __restrict__ mcnt_m,
    const int* __restrict__ cnt_l, const int* __restrict__ rank_l,
    int* __restrict__ clist_l, int* __restrict__ mcnt_l) {
  int bid = blockIdx.x;
  if (bid < NPTS/BLK) {
    int i = bid * BLK + threadIdx.x;
    float b = pts[i*5+0], x = pts[i*5+1], y = pts[i*5+2], z = pts[i*5+3], it = pts[i*5+4];
    float4 p; p.x = x; p.y = y; p.z = z; p.w = it;
    {
      int r = rkt[lin3(b,x,y,z, 0.4f,0.4f,4.0f, 176,200,1)];
      int j = atomicAdd(&wot[r], 1); st[j] = p; jt[j] = r;
    }
    {
      int r = rkm[lin3(b,x,y,z, 0.2f,0.2f,2.0f, 352,400,2)];
      int j = atomicAdd(&wom[r], 1); sm[j] = p; jm[j] = r;
    }
    {
      int r = rkl[lin3(b,x,y,z, 0.1f,0.1f,1.0f, 704,800,4)];
      int j = atomicAdd(&wol[r], 1); sl[j] = p; jl[j] = r;
    }
    return;
  }
  int cb = bid - NPTS/BLK;
  const int *scnt, *srank; int *clist, *mcnt;
  int gx, gy, gz, f, rb;
  if (cb < NCL) { scnt=cnt_m; srank=rank_m; clist=clist_m; mcnt=mcnt_m;
                  gx=352; gy=400; gz=2; f=2; rb=cb; }
  else          { scnt=cnt_l; srank=rank_l; clist=clist_l; mcnt=mcnt_l;
                  gx=704; gy=800; gz=4; f=4; rb=cb-NCL; }
  int r = rb * BLK + threadIdx.x;
  if (r >= *Utp) return;
  int lin = tuniq[r];
  int x = lin % TGX; int t = lin / TGX;
  int y = t % TGY;   int b = t / TGY;   // TGZ == 1 so z == 0
  int m = 0;
  for (int cz = 0; cz < gz; cz++)
    for (int yy = y*f; yy < y*f + f; yy++)
      for (int xx = x*f; xx < x*f + f; xx++) {
        int cl = ((b*gz + cz)*gy + yy)*gx + xx;
        if (scnt[cl] > 0) clist[(size_t)r*64 + (m++)] = srank[cl];
      }
  mcnt[r] = m;
}

// ---------------- batched per-voxel xyz means ----------------
__global__ __launch_bounds__(BLK) void k_vox13(
    const float4* __restrict__ st, const int* __restrict__ uqt, const int* __restrict__ ct,
    const int* __restrict__ wot, const int* __restrict__ Ut, float4* __restrict__ vt,
    const float4* __restrict__ sm, const int* __restrict__ uqm, const int* __restrict__ cm,
    const int* __restrict__ wom, const int* __restrict__ Um, float4* __restrict__ vm,
    const float4* __restrict__ sl, const int* __restrict__ uql, const int* __restrict__ cl,
    const int* __restrict__ wol, const int* __restrict__ Ul, float4* __restrict__ vl) {
  int bid = blockIdx.x;
  const float4* srt; const int *uniq, *cnt, *woff, *Up; float4* vmean; int r;
  if (bid < NBVT)           { r = bid*BLK + threadIdx.x;           srt=st; uniq=uqt; cnt=ct; woff=wot; Up=Ut; vmean=vt; }
  else if (bid < NBVT+NBVM) { r = (bid-NBVT)*BLK + threadIdx.x;    srt=sm; uniq=uqm; cnt=cm; woff=wom; Up=Um; vmean=vm; }
  else                      { r = (bid-NBVT-NBVM)*BLK + threadIdx.x; srt=sl; uniq=uql; cnt=cl; woff=wol; Up=Ul; vmean=vl; }
  if (r >= *Up) return;
  int lin = uniq[r];
  int len = cnt[lin];
  int base = woff[r] - len;
  float sx = 0.f, sy = 0.f, sz = 0.f;
  for (int k = 0; k < len; k++) {
    float4 p = srt[base + k];
    sx += p.x; sy += p.y; sz += p.z;
  }
  float il = 1.0f / (float)len;
  float4 o; o.x = sx*il; o.y = sy*il; o.z = sz*il; o.w = il;
  vmean[r] = o;
}

// ------- f-moment partials (65 values: 10 means + 55 upper-tri products) ----
__global__ __launch_bounds__(BLK) void k_fmom_all(SP a, SP b, SP c) {
  int s = blockIdx.x >> 8;
  int blk = blockIdx.x & 255;
  SP sp = (s == 0) ? a : ((s == 1) ? b : c);
  float m[65];
  #pragma unroll
  for (int i = 0; i < 65; i++) m[i] = 0.f;
  #pragma unroll
  for (int k = 0; k < 4; k++) {
    int i = blk*1024 + k*BLK + threadIdx.x;
    float4 p = sp.srt[i];
    float4 vmn = sp.vm[sp.jr[i]];
    float f[10];
    build_f(p, vmn, sp.vx, sp.vy, sp.vz, sp.gx, sp.gy, sp.gz, f);
    int idx = 10;
    #pragma unroll
    for (int d = 0; d < 10; d++) {
      m[d] += f[d];
      #pragma unroll
      for (int e = d; e < 10; e++) {
        m[idx] = fmaf(f[d], f[e], m[idx]);
        idx++;
      }
    }
  }
  #pragma unroll
  for (int st = 1; st < 64; st <<= 1) {
    #pragma unroll
    for (int i = 0; i < 65; i++) m[i] += __shfl_xor(m[i], st);
  }
  __shared__ float ws[4][65];
  int wv = threadIdx.x >> 6;
  int lane = threadIdx.x & 63;
  if (lane == 0) {
    #pragma unroll
    for (int i = 0; i < 65; i++) ws[wv][i] = m[i];
  }
  __syncthreads();
  if (threadIdx.x < 65) {
    int t = threadIdx.x;
    sp.part1[(size_t)blk*65 + t] = ws[0][t] + ws[1][t] + ws[2][t] + ws[3][t];
  }
}

// ---- reduce f-moments -> BN1 coef via mu = E[f]^T w, E[y^2] = w^T M w ------
__global__ __launch_bounds__(BLK) void k_mcoef_all(SP a, SP b, SP c) {
  SP sp = (blockIdx.x == 0) ? a : ((blockIdx.x == 1) ? b : c);
  const int C1 = sp.C1;
  __shared__ float M[65];
  int t = threadIdx.x;
  if (t < 65) {
    float s = 0.f;
    #pragma unroll 8
    for (int bk = 0; bk < ST1BLKS; bk++) s += sp.part1[(size_t)bk*65 + t];
    M[t] = s * (1.0f / NPTS);
  }
  __syncthreads();
  if (t < C1) {
    float wv[10];
    #pragma unroll
    for (int d = 0; d < 10; d++) wv[d] = sp.W1[d*C1 + t];
    float mu = 0.f;
    #pragma unroll
    for (int d = 0; d < 10; d++) mu = fmaf(M[d], wv[d], mu);
    float ey2 = 0.f;
    int idx = 10;
    #pragma unroll
    for (int d = 0; d < 10; d++) {
      #pragma unroll
      for (int e = d; e < 10; e++) {
        float c2 = M[idx] * wv[d] * wv[e];
        ey2 += (e == d) ? c2 : 2.0f * c2;
        idx++;
      }
    }
    float var = ey2 - mu*mu;
    float sc  = sp.g1[t] * (1.0f / sqrtf(var + 1e-3f));
    sp.coef1[t]      = sc;
    sp.coef1[C1 + t] = fmaf(-mu, sc, sp.b1[t]);
  }
}

// ---- layer-2 stats partials reduce -> BN2 coef -----------------------------
__device__ __forceinline__ void partcoef_body(const float* part, int NB, int C,
    int ch, const float* g, const float* b, float* coef) {
  float s = 0.f, q = 0.f;
  for (int bk = threadIdx.x; bk < NB; bk += BLK) {
    s += part[(size_t)bk*2*C + ch];
    q += part[(size_t)bk*2*C + C + ch];
  }
  __shared__ float ss[BLK], sq[BLK];
  ss[threadIdx.x] = s; sq[threadIdx.x] = q; __syncthreads();
  for (int off = BLK/2; off > 0; off >>= 1) {
    if (threadIdx.x < off) {
      ss[threadIdx.x] += ss[threadIdx.x + off];
      sq[threadIdx.x] += sq[threadIdx.x + off];
    }
    __syncthreads();
  }
  if (threadIdx.x == 0) {
    float mu  = ss[0] * (1.0f / NPTS);
    float var = sq[0] * (1.0f / NPTS) - mu*mu;
    float sc  = g[ch] * (1.0f / sqrtf(var + 1e-3f));
    coef[ch]     = sc;
    coef[C + ch] = fmaf(-mu, sc, b[ch]);
  }
}

__global__ __launch_bounds__(BLK) void k_partcoef2_all(SP a, SP b, SP c) {
  int bid = blockIdx.x; SP sp; int ch;
  if (bid < 128)      { sp = a; ch = bid; }
  else if (bid < 192) { sp = b; ch = bid - 128; }
  else                { sp = c; ch = bid - 192; }
  if (ch >= 2*sp.C1) return;
  partcoef_body(sp.part2, Y2B2, 2*sp.C1, ch, sp.g2, sp.b2, sp.coef2);
}

// ---- layer-1 voxel means of BN+ReLU(y1), 8 ch/thread, row-major bf16 out ---
__global__ __launch_bounds__(BLK) void k_hsegT_all(SP a, SP b, SP c) {
  int bid = blockIdx.x; SP sp; int rb;
  if (bid < NHT2)           { sp = a; rb = bid; }
  else if (bid < NHT2+NHM2) { sp = b; rb = bid - NHT2; }
  else                      { sp = c; rb = bid - NHT2 - NHM2; }
  const int C1 = sp.C1;
  const int qsh = (C1 == 64) ? 3 : 2;      // threads per voxel = C1/8
  __shared__ float w[640];
  __shared__ float sc[64], sb[64];
  for (int t = threadIdx.x; t < 10*C1; t += BLK) w[t] = sp.W1[t];
  for (int t = threadIdx.x; t < C1; t += BLK) { sc[t] = sp.coef1[t]; sb[t] = sp.coef1[C1 + t]; }
  __syncthreads();
  int tid = rb * BLK + threadIdx.x;
  int r = tid >> qsh;
  int q = tid & ((1 << qsh) - 1);
  if (r >= *sp.U) return;
  int lin = sp.uniq[r];
  int len = sp.cnt[lin];
  int base = sp.woff[r] - len;
  float4 vmn = sp.vm[r];
  int c0 = q * 8;
  float s[8], o[8], acc[8];
  #pragma unroll
  for (int e = 0; e < 8; e++) { s[e] = sc[c0+e]; o[e] = sb[c0+e]; acc[e] = 0.f; }
  for (int k = 0; k < len; k++) {
    float4 p = sp.srt[base + k];
    float f[10];
    build_f(p, vmn, sp.vx, sp.vy, sp.vz, sp.gx, sp.gy, sp.gz, f);
    float y[8] = {0,0,0,0,0,0,0,0};
    #pragma unroll
    for (int d = 0; d < 10; d++) {
      float fv = f[d];
      const float* wr = &w[d*C1 + c0];
      #pragma unroll
      for (int e = 0; e < 8; e++) y[e] = fmaf(fv, wr[e], y[e]);
    }
    #pragma unroll
    for (int e = 0; e < 8; e++) acc[e] += fmaxf(fmaf(y[e], s[e], o[e]), 0.f);
  }
  float il = 1.0f / (float)len;
  ushort4 h0, h1;
  h0.x = f2bf(acc[0]*il); h0.y = f2bf(acc[1]*il);
  h0.z = f2bf(acc[2]*il); h0.w = f2bf(acc[3]*il);
  h1.x = f2bf(acc[4]*il); h1.y = f2bf(acc[5]*il);
  h1.z = f2bf(acc[6]*il); h1.w = f2bf(acc[7]*il);
  *(ushort4*)&sp.segt[(size_t)r*C1 + c0]     = h0;
  *(ushort4*)&sp.segt[(size_t)r*C1 + c0 + 4] = h1;
}

// ------- layer 2 as MFMA bf16 GEMM (64-row tiles); fused column stats -------
template<int C1>
__device__ __forceinline__ void y2m_body(const SP& sp,
    const unsigned short* __restrict__ Bpk, int blk, unsigned short* Alds) {
  constexpr int K   = 2*C1;
  constexpr int C2  = 2*C1;
  constexpr int MT  = 64;
  constexpr int NKB = K / 32;          // 4 (top), 2 (med/low)
  constexpr int NCF = C2 / 16;         // 8 (top), 4 (med/low)
  constexpr int RB  = K * 2;           // row bytes in Alds
  const int tid  = threadIdx.x;
  const int base = blk * MT;

  // ---- stage A tile (bf16, XOR-swizzled): 4 threads/row, K/4 channels each
  {
    const int jst = tid & 63;
    const int qst = tid >> 6;          // wave id == channel-quarter (wave-uniform)
    int jr = sp.jr[base + jst];
    float4 p = sp.srt[base + jst];
    float4 vmn = sp.vm[jr];
    float fs[10];
    build_f(p, vmn, sp.vx, sp.vy, sp.vz, sp.gx, sp.gy, sp.gz, fs);
    const int k_lo = qst * (K/4);
    #pragma unroll
    for (int kk = 0; kk < K/8; kk++) {
      int k0 = k_lo + kk*2;
      unsigned u;
      if (k0 < C1) {
        float y0 = 0.f, y1v = 0.f;
        #pragma unroll
        for (int d = 0; d < 10; d++) {
          y0  = fmaf(fs[d], sp.W1[d*C1 + k0],     y0);
          y1v = fmaf(fs[d], sp.W1[d*C1 + k0 + 1], y1v);
        }
        float v0 = fmaxf(fmaf(y0,  sp.coef1[k0],   sp.coef1[C1 + k0]),   0.f);
        float v1 = fmaxf(fmaf(y1v, sp.coef1[k0+1], sp.coef1[C1 + k0+1]), 0.f);
        u = (unsigned)f2bf(v0) | ((unsigned)f2bf(v1) << 16);
      } else {
        // row-major segt: contiguous bf16 pair load (4B, aligned)
        u = *(const unsigned*)&sp.segt[(size_t)jr*C1 + (k0 - C1)];
      }
      int g  = k0 >> 3;
      int gp = g ^ (jst & 7);
      *(unsigned*)((char*)Alds + (size_t)jst*RB + gp*16 + (k0 & 7)*2) = u;
    }
  }
  __syncthreads();

  // ---- MFMA main loop: wave w owns rows [w*16, w*16+16) ----
  const int w    = tid >> 6;
  const int l    = tid & 63;
  const int rowf = l & 15;
  const int kg   = l >> 4;
  const int row  = w*16 + rowf;
  f32x4 acc[NCF];
  #pragma unroll
  for (int cf = 0; cf < NCF; cf++) acc[cf] = (f32x4){0.f, 0.f, 0.f, 0.f};
  #pragma unroll
  for (int kb = 0; kb < NKB; kb++) {
    int g  = kb*4 + kg;
    int gp = g ^ (row & 7);
    bf16x8 a = *(const bf16x8*)((const char*)Alds + (size_t)row*RB + gp*16);
    const bf16x8* bfr = (const bf16x8*)Bpk + (size_t)(kb*NCF)*64 + l;
    #pragma unroll
    for (int cf = 0; cf < NCF; cf++) {
      bf16x8 b = bfr[cf*64];
      acc[cf] = __builtin_amdgcn_mfma_f32_16x16x32_bf16(a, b, acc[cf], 0, 0, 0);
    }
  }

  // ---- fused column sum/sumsq partials from fp32 acc (reuse Alds) ----
  __syncthreads();
  float* red = (float*)Alds;           // [32][C2] floats == Alds byte size
  #pragma unroll
  for (int cf = 0; cf < NCF; cf++) {
    f32x4 v = acc[cf];
    float sv = v.x + v.y + v.z + v.w;
    float qv = v.x*v.x + v.y*v.y + v.z*v.z + v.w*v.w;
    red[(w*4 + kg)*C2 + cf*16 + rowf]        = sv;
    red[(16 + w*4 + kg)*C2 + cf*16 + rowf]   = qv;
  }
  __syncthreads();
  if (tid < C2) {
    float sv = 0.f, qv = 0.f;
    #pragma unroll 4
    for (int i = 0; i < 16; i++) {
      sv += red[i*C2 + tid];
      qv += red[(16 + i)*C2 + tid];
    }
    sp.part2[(size_t)blk*2*C2 + tid]      = sv;
    sp.part2[(size_t)blk*2*C2 + C2 + tid] = qv;
  }
  __syncthreads();

  // ---- D -> LDS (bf16, row-major) -> coalesced global store ----
  unsigned short* D = Alds;
  #pragma unroll
  for (int cf = 0; cf < NCF; cf++) {
    #pragma unroll
    for (int rg = 0; rg < 4; rg++) {
      int rr = w*16 + kg*4 + rg;       // C/D: col=lane&15, row=(lane>>4)*4+reg
      D[rr*C2 + cf*16 + rowf] = f2bf(acc[cf][rg]);
    }
  }
  __syncthreads();
  for (int it = tid; it < MT*C2/8; it += BLK) {
    int r = (it*8) / C2;
    int c = (it*8) % C2;
    uint4 v = *(const uint4*)&D[it*8];
    *(uint4*)&sp.Y2[(size_t)(base + r)*C2 + c] = v;
  }
}

__global__ __launch_bounds__(BLK) void k_y2m_all(SP a, SP b, SP c,
    const unsigned short* __restrict__ Bt, const unsigned short* __restrict__ Bm,
    const unsigned short* __restrict__ Bl) {
  __shared__ unsigned short Alds[64*128];   // 16 KB (med/low use half)
  int bid = blockIdx.x;
  if (bid < Y2B2)        y2m_body<64>(a, Bt, bid, Alds);
  else if (bid < 2*Y2B2) y2m_body<32>(b, Bm, bid - Y2B2, Alds);
  else                   y2m_body<32>(c, Bl, bid - 2*Y2B2, Alds);
}

// -------- layer-2 BN+ReLU + voxel mean (bf16 Y2, 8 channels/thread) ---------
__global__ __launch_bounds__(BLK) void k_hseg2_all(SP a, SP b, SP c) {
  int bid = blockIdx.x; SP sp; int rb;
  if (bid < NJT2)           { sp = a; rb = bid; }
  else if (bid < NJT2+NJM2) { sp = b; rb = bid - NJT2; }
  else                      { sp = c; rb = bid - NJT2 - NJM2; }
  const int C = 2*sp.C1;
  const int qsh = (C == 128) ? 4 : 3;      // threads per voxel = C/8
  __shared__ float sc[128], sb[128];
  for (int t = threadIdx.x; t < C; t += BLK) { sc[t] = sp.coef2[t]; sb[t] = sp.coef2[C + t]; }
  __syncthreads();
  int tid = rb * BLK + threadIdx.x;
  int r = tid >> qsh;
  int q = tid & ((1 << qsh) - 1);
  if (r >= *sp.U) return;
  int lin = sp.uniq[r];
  int len = sp.cnt[lin];
  int base = sp.woff[r] - len;
  int c0 = q * 8;
  float s[8], o[8], acc[8];
  #pragma unroll
  for (int e = 0; e < 8; e++) { s[e] = sc[c0+e]; o[e] = sb[c0+e]; acc[e] = 0.f; }
  const unsigned short* Yh = sp.Y2;
  for (int k = 0; k < len; k++) {
    uint4 hv = *(const uint4*)&Yh[(size_t)(base + k)*C + c0];
    unsigned uu[4] = {hv.x, hv.y, hv.z, hv.w};
    #pragma unroll
    for (int j = 0; j < 4; j++) {
      float lo = __uint_as_float(uu[j] << 16);
      float hi = __uint_as_float(uu[j] & 0xFFFF0000u);
      acc[2*j+0] += fmaxf(fmaf(lo, s[2*j+0], o[2*j+0]), 0.f);
      acc[2*j+1] += fmaxf(fmaf(hi, s[2*j+1], o[2*j+1]), 0.f);
    }
  }
  float il = 1.0f / (float)len;
  float4 o0 = {acc[0]*il, acc[1]*il, acc[2]*il, acc[3]*il};
  float4 o1 = {acc[4]*il, acc[5]*il, acc[6]*il, acc[7]*il};
  *(float4*)&sp.hout[(size_t)r*C + c0]     = o0;
  *(float4*)&sp.hout[(size_t)r*C + c0 + 4] = o1;
}

// ---- fused: merge means into mg (r<U) + tail zero + coors ------------------
__global__ __launch_bounds__(BLK) void k_mergefin(
    const float* __restrict__ vox_m, const int* __restrict__ clist_m,
    const int* __restrict__ mcnt_m,
    const float* __restrict__ vox_l, const int* __restrict__ clist_l,
    const int* __restrict__ mcnt_l,
    const int* __restrict__ uniq, const int* __restrict__ Up,
    float* __restrict__ vf, float* __restrict__ mg, float* __restrict__ coors) {
  int bid = blockIdx.x;
  if (bid < 2*NMG) {
    const float* vox; const int *clist, *mcnt; int half, rb;
    if (bid < NMG) { vox=vox_m; clist=clist_m; mcnt=mcnt_m; half=0; rb=bid; }
    else           { vox=vox_l; clist=clist_l; mcnt=mcnt_l; half=64; rb=bid-NMG; }
    int idx = rb * BLK + threadIdx.x;
    int r = idx >> 4;
    int q = idx & 15;
    if (r >= *Up) return;
    int m = mcnt[r];
    float a0=0.f, a1=0.f, a2=0.f, a3=0.f;
    for (int t = 0; t < m; t++) {
      int cr = clist[(size_t)r*64 + t];
      float4 v = *(const float4*)&vox[(size_t)cr*64 + q*4];
      a0 += v.x; a1 += v.y; a2 += v.z; a3 += v.w;
    }
    float inv = 1.0f / (float)max(m, 1);
    float4 o = {a0*inv, a1*inv, a2*inv, a3*inv};
    *(float4*)&mg[(size_t)r*128 + half + q*4] = o;
    return;
  }
  int idx = (bid - 2*NMG) * BLK + threadIdx.x;
  int r = idx >> 5;
  int q = idx & 31;
  if (r >= NPTS) return;
  int U = *Up;
  if (r >= U) {
    float4 z = {0.f, 0.f, 0.f, 0.f};
    *(float4*)&mg[(size_t)r*128 + q*4] = z;
    *(float4*)&vf[(size_t)r*128 + q*4] = z;
  }
  if (q == 0) {
    float4 co;
    if (r < U) {
      int lin = uniq[r];
      int x = lin % TGX; int t = lin / TGX;
      int y = t % TGY;   t /= TGY;
      int z = t % TGZ;   int b = t / TGZ;
      co.x = (float)b; co.y = (float)z; co.z = (float)y; co.w = (float)x;
    } else {
      co.x = -1.f; co.y = -1.f; co.z = -1.f; co.w = -1.f;
    }
    *(float4*)&coors[(size_t)r*4] = co;
  }
}

extern "C" void kernel_launch(void* const* d_in, const int* in_sizes, int n_in,
                              void* d_out, int out_size, void* d_ws, size_t ws_size,
                              hipStream_t stream) {
  const float* pts = (const float*)d_in[0];

  float* out = (float*)d_out;
  float* vf = out;                              // N x 128 (final vf)
  float* mg = out + (size_t)NPTS * 128;         // N x 128 (merged)
  float* co = out + (size_t)NPTS * 256;         // N x 4   (coors)

  char* w = (char*)d_ws;
  size_t off = 0;
  auto alloc = [&](size_t bytes) -> void* {
    void* p = w + off;
    off = (off + bytes + 1023) & ~(size_t)1023;
    return p;
  };
  int*    cnt_t   = (int*)alloc(((size_t)G_TOPC + G_MEDC + G_LOWC) * 4);
  int*    cnt_m   = cnt_t + G_TOPC;
  int*    cnt_l   = cnt_t + G_TOPC + G_MEDC;
  int*    rank_t  = (int*)alloc((size_t)G_TOPC * 4);
  int*    rank_m  = (int*)alloc((size_t)G_MEDC * 4);
  int*    rank_l  = (int*)alloc((size_t)G_LOWC * 4);
  int*    uniq_t  = (int*)alloc((size_t)G_TOPC * 4);
  int*    uniq_m  = (int*)alloc((size_t)NPTS * 4);
  int*    uniq_l  = (int*)alloc((size_t)NPTS * 4);
  int*    woff_t  = (int*)alloc((size_t)G_TOPC * 4);
  int*    woff_m  = (int*)alloc((size_t)NPTS * 4);
  int*    woff_l  = (int*)alloc((size_t)NPTS * 4);
  float4* srt_t   = (float4*)alloc((size_t)NPTS * 16);
  float4* srt_m   = (float4*)alloc((size_t)NPTS * 16);
  float4* srt_l   = (float4*)alloc((size_t)NPTS * 16);
  int*    jr_t    = (int*)alloc((size_t)NPTS * 4);
  int*    jr_m    = (int*)alloc((size_t)NPTS * 4);
  int*    jr_l    = (int*)alloc((size_t)NPTS * 4);
  float4* vm_t    = (float4*)alloc((size_t)G_TOPC * 16);
  float4* vm_m    = (float4*)alloc((size_t)NPTS * 16);
  float4* vm_l    = (float4*)alloc((size_t)NPTS * 16);
  unsigned short* segt_t = (unsigned short*)alloc((size_t)G_TOPC * 64 * 2);
  unsigned short* segt_m = (unsigned short*)alloc((size_t)NPTS * 32 * 2);
  unsigned short* segt_l = (unsigned short*)alloc((size_t)NPTS * 32 * 2);
  float*  vox_m   = (float*)alloc((size_t)NPTS * 64 * 4);
  float*  vox_l   = (float*)alloc((size_t)NPTS * 64 * 4);
  unsigned short* Y2h_t = (unsigned short*)alloc((size_t)NPTS * 128 * 2);
  unsigned short* Y2h_m = (unsigned short*)alloc((size_t)NPTS * 64 * 2);
  unsigned short* Y2h_l = (unsigned short*)alloc((size_t)NPTS * 64 * 2);
  unsigned short* Bpk_t = (unsigned short*)alloc(16384 * 2);
  unsigned short* Bpk_m = (unsigned short*)alloc(4096 * 2);
  unsigned short* Bpk_l = (unsigned short*)alloc(4096 * 2);
  int*    clist_m = (int*)alloc((size_t)G_TOPC * 64 * 4);
  int*    clist_l = (int*)alloc((size_t)G_TOPC * 64 * 4);
  int*    mcnt_m  = (int*)alloc((size_t)G_TOPC * 4);
  int*    mcnt_l  = (int*)alloc((size_t)G_TOPC * 4);
  float*  part1_t = (float*)alloc((size_t)ST1BLKS * 128 * 4);
  float*  part1_m = (float*)alloc((size_t)ST1BLKS * 128 * 4);
  float*  part1_l = (float*)alloc((size_t)ST1BLKS * 128 * 4);
  float*  part2_t = (float*)alloc((size_t)Y2B2 * 256 * 4);
  float*  part2_m = (float*)alloc((size_t)Y2B2 * 128 * 4);
  float*  part2_l = (float*)alloc((size_t)Y2B2 * 128 * 4);
  float*  coef    = (float*)alloc(6 * 256 * 4);
  int2*   bsum    = (int2*)alloc(1024 * 8);
  int*    Ut      = (int*)alloc(64);
  int*    Um      = (int*)alloc(64);
  int*    Ul      = (int*)alloc(64);
  (void)in_sizes; (void)n_in; (void)out_size; (void)ws_size;

  auto mkSP = [&](int scaleIdx) -> SP {
    SP s{};
    if (scaleIdx == 0) {
      s.srt = srt_t; s.jr = jr_t; s.vm = vm_t;
      s.W1 = (const float*)d_in[2];  s.g1 = (const float*)d_in[3];
      s.b1 = (const float*)d_in[4];  s.W2 = (const float*)d_in[5];
      s.g2 = (const float*)d_in[6];  s.b2 = (const float*)d_in[7];
      s.cnt = cnt_t; s.uniq = uniq_t; s.woff = woff_t; s.U = Ut;
      s.segt = segt_t; s.part1 = part1_t; s.part2 = part2_t;
      s.coef1 = coef + 0*256; s.coef2 = coef + 1*256;
      s.Y2 = Y2h_t; s.hout = vf;
      s.C1 = 64; s.segstride = 64;
      s.gx = 176; s.gy = 200; s.gz = 1; s.vx = 0.4f; s.vy = 0.4f; s.vz = 4.0f;
    } else if (scaleIdx == 1) {
      s.srt = srt_m; s.jr = jr_m; s.vm = vm_m;
      s.W1 = (const float*)d_in[8];  s.g1 = (const float*)d_in[9];
      s.b1 = (const float*)d_in[10]; s.W2 = (const float*)d_in[11];
      s.g2 = (const float*)d_in[12]; s.b2 = (const float*)d_in[13];
      s.cnt = cnt_m; s.uniq = uniq_m; s.woff = woff_m; s.U = Um;
      s.segt = segt_m; s.part1 = part1_m; s.part2 = part2_m;
      s.coef1 = coef + 2*256; s.coef2 = coef + 3*256;
      s.Y2 = Y2h_m; s.hout = vox_m;
      s.C1 = 32; s.segstride = 32;
      s.gx = 352; s.gy = 400; s.gz = 2; s.vx = 0.2f; s.vy = 0.2f; s.vz = 2.0f;
    } else {
      s.srt = srt_l; s.jr = jr_l; s.vm = vm_l;
      s.W1 = (const float*)d_in[14]; s.g1 = (const float*)d_in[15];
      s.b1 = (const float*)d_in[16]; s.W2 = (const float*)d_in[17];
      s.g2 = (const float*)d_in[18]; s.b2 = (const float*)d_in[19];
      s.cnt = cnt_l; s.uniq = uniq_l; s.woff = woff_l; s.U = Ul;
      s.segt = segt_l; s.part1 = part1_l; s.part2 = part2_l;
      s.coef1 = coef + 4*256; s.coef2 = coef + 5*256;
      s.Y2 = Y2h_l; s.hout = vox_l;
      s.C1 = 32; s.segstride = 32;
      s.gx = 704; s.gy = 800; s.gz = 4; s.vx = 0.1f; s.vy = 0.1f; s.vz = 1.0f;
    }
    return s;
  };
  SP spT = mkSP(0), spM = mkSP(1), spL = mkSP(2);

  // ---- batched voxelization front-end ----
  (void)hipMemsetAsync(cnt_t, 0, ((size_t)G_TOPC + G_MEDC + G_LOWC) * 4, stream);
  k_count3pack<<<NPTS/BLK + 96, BLK, 0, stream>>>(pts, cnt_t, cnt_m, cnt_l,
      (const float*)d_in[5], Bpk_t, (const float*)d_in[11], Bpk_m,
      (const float*)d_in[17], Bpk_l);
  k_scan1_all<<<NB_T + NB_M + NB_L, BLK, 0, stream>>>(cnt_t, cnt_m, cnt_l, bsum);
  k_scan2_all<<<1, 192, 0, stream>>>(bsum, Ut, Um, Ul);
  k_scan3_all<<<NB_T + NB_M + NB_L, BLK, 0, stream>>>(cnt_t, cnt_m, cnt_l, bsum,
      rank_t, rank_m, rank_l, uniq_t, uniq_m, uniq_l, woff_t, woff_m, woff_l);
  k_scatclist<<<NPTS/BLK + 2*NCL, BLK, 0, stream>>>(pts,
      rank_t, woff_t, srt_t, jr_t,
      rank_m, woff_m, srt_m, jr_m,
      rank_l, woff_l, srt_l, jr_l,
      uniq_t, Ut, cnt_m, rank_m, clist_m, mcnt_m, cnt_l, rank_l, clist_l, mcnt_l);
  k_vox13<<<NBVT + NBVM + NBVL, BLK, 0, stream>>>(
      srt_t, uniq_t, cnt_t, woff_t, Ut, vm_t,
      srt_m, uniq_m, cnt_m, woff_m, Um, vm_m,
      srt_l, uniq_l, cnt_l, woff_l, Ul, vm_l);

  // ---- batched VFE pipeline (all scales per stage) ----
  k_fmom_all<<<3*ST1BLKS, BLK, 0, stream>>>(spT, spM, spL);
  k_mcoef_all<<<3, BLK, 0, stream>>>(spT, spM, spL);
  k_hsegT_all<<<NHT2 + 2*NHM2, BLK, 0, stream>>>(spT, spM, spL);
  k_y2m_all<<<3*Y2B2, BLK, 0, stream>>>(spT, spM, spL, Bpk_t, Bpk_m, Bpk_l);
  k_partcoef2_all<<<256, BLK, 0, stream>>>(spT, spM, spL);
  k_hseg2_all<<<NJT2 + 2*NJM2, BLK, 0, stream>>>(spT, spM, spL);

  // ---- merges + final outputs (one kernel) ----
  k_mergefin<<<2*NMG + FINB, BLK, 0, stream>>>(vox_m, clist_m, mcnt_m,
      vox_l, clist_l, mcnt_l, uniq_t, Ut, vf, mg, co);
}

// Round 15
// 609.262 us; speedup vs baseline: 1.0218x; 1.0218x over previous
//
#include <hip/hip_runtime.h>
#include <cstdint>
#include <cstddef>

#define NPTS 262144
#define BLK 256
#define TGX 176
#define TGY 200
#define TGZ 1

#define G_TOPC 70400
#define G_MEDC 1126400
#define G_LOWC 4505600

#define SCAN_ITEMS 32
#define SCAN_CHUNK (BLK*SCAN_ITEMS)
// batched scan block counts / bsum offsets (disjoint: [0,9) [16,154) [160,710))
#define NB_T 9
#define NB_M 138
#define NB_L 550
#define BO_T 0
#define BO_M 16
#define BO_L 160
// vox13 block split
#define NBVT (G_TOPC/BLK)      // 275
#define NBVM (NPTS/BLK)        // 1024
#define NBVL (NPTS/BLK)        // 1024

#define Y2B2 (NPTS/64)         // 4096 blocks per scale (64-row MFMA tiles)
#define ST1BLKS 256            // fmom blocks per scale (1024 rows each)
// batched per-scale stage grids
#define NHT2 2200              // G_TOPC*8/BLK   (hsegT top, 8 ch/thread)
#define NHM2 4096              // NPTS*4/BLK     (hsegT med/low)
#define NJT2 4400              // G_TOPC*16/BLK  (hseg2 top, 8 ch/thread)
#define NJM2 8192              // NPTS*8/BLK     (hseg2 med/low)
#define NMG 4400               // G_TOPC*16/BLK  (merge, 16 thr/voxel)
#define FINB 32768             // NPTS*32/BLK    (fin)
#define NCL 275                // G_TOPC/BLK (ceil)

typedef __attribute__((ext_vector_type(8))) short bf16x8;
typedef __attribute__((ext_vector_type(4))) float f32x4;

// ---------------- per-scale parameter pack ----------------
struct SP {
  const float4* srt; const int* jr; const float4* vm;
  const float* W1; const float* W2;
  const float* g1; const float* b1; const float* g2; const float* b2;
  const int* cnt; const int* uniq; const int* woff; const int* U;
  unsigned short* segt;        // bf16 storage (lossless: only consumed as bf16)
  float* part1; float* part2;
  float* coef1; float* coef2;
  unsigned short* Y2;          // bf16 storage
  float* hout;
  int C1; int segstride; int gx, gy, gz; float vx, vy, vz;
};

// ---------------- bf16 helpers ----------------
__device__ __forceinline__ unsigned short f2bf(float v) {
  unsigned u = __float_as_uint(v);
  u += 0x7FFFu + ((u >> 16) & 1u);      // round-to-nearest-even
  return (unsigned short)(u >> 16);
}
__device__ __forceinline__ float bf2f(unsigned short h) {
  return __uint_as_float((unsigned)h << 16);
}

// ---------------- voxel coord helpers ----------------
__device__ __forceinline__ void pcoords(float x, float y, float z,
    float vx, float vy, float vz, int gx, int gy, int gz,
    int& cx, int& cy, int& cz) {
  cx = (int)floorf((x - 0.0f)  / vx);
  cy = (int)floorf((y + 40.0f) / vy);
  cz = (int)floorf((z + 3.0f)  / vz);
  cx = min(max(cx, 0), gx - 1);
  cy = min(max(cy, 0), gy - 1);
  cz = min(max(cz, 0), gz - 1);
}

__device__ __forceinline__ int lin3(float b, float x, float y, float z,
    float vx, float vy, float vz, int gx, int gy, int gz) {
  int cx, cy, cz; pcoords(x, y, z, vx, vy, vz, gx, gy, gz, cx, cy, cz);
  return (((int)b * gz + cz) * gy + cy) * gx + cx;
}

// f-vector (10 features) — identical expression everywhere y1 is recomputed.
__device__ __forceinline__ void build_f(float4 p, float4 vm,
    float vx, float vy, float vz, int gx, int gy, int gz, float* f) {
  int cx, cy, cz; pcoords(p.x, p.y, p.z, vx, vy, vz, gx, gy, gz, cx, cy, cz);
  f[0] = p.x; f[1] = p.y; f[2] = p.z; f[3] = p.w;
  f[4] = p.x - vm.x;
  f[5] = p.y - vm.y;
  f[6] = p.z - vm.z;
  f[7] = p.x - (0.0f   + (cx + 0.5f)*vx);
  f[8] = p.y - (-40.0f + (cy + 0.5f)*vy);
  f[9] = p.z - (-3.0f  + (cz + 0.5f)*vz);
}

// ------- fused: dense count (3 scales) + W2 bf16 fragment pre-pack ----------
__global__ __launch_bounds__(BLK) void k_count3pack(const float* __restrict__ pts,
    int* __restrict__ ct, int* __restrict__ cm, int* __restrict__ cl,
    const float* __restrict__ W2t_, unsigned short* __restrict__ Bt,
    const float* __restrict__ W2m_, unsigned short* __restrict__ Bm,
    const float* __restrict__ W2l_, unsigned short* __restrict__ Bl) {
  int bid = blockIdx.x;
  if (bid < NPTS/BLK) {
    int i = bid * BLK + threadIdx.x;
    float b = pts[i*5+0], x = pts[i*5+1], y = pts[i*5+2], z = pts[i*5+3];
    atomicAdd(&ct[lin3(b,x,y,z, 0.4f,0.4f,4.0f, 176,200,1)], 1);
    atomicAdd(&cm[lin3(b,x,y,z, 0.2f,0.2f,2.0f, 352,400,2)], 1);
    atomicAdd(&cl[lin3(b,x,y,z, 0.1f,0.1f,1.0f, 704,800,4)], 1);
    return;
  }
  int pb = bid - NPTS/BLK;
  const float* W2; unsigned short* Bp; int C2, idx;
  if (pb < 64)      { W2 = W2t_; Bp = Bt; C2 = 128; idx = pb*BLK + threadIdx.x; }
  else if (pb < 80) { W2 = W2m_; Bp = Bm; C2 = 64;  idx = (pb-64)*BLK + threadIdx.x; }
  else              { W2 = W2l_; Bp = Bl; C2 = 64;  idx = (pb-80)*BLK + threadIdx.x; }
  if (idx >= C2*C2) return;            // K == C2 for all scales
  int NCF = C2/16;
  int per_kb = NCF*512;
  int kb = idx / per_kb, rem = idx % per_kb;
  int cf = rem / 512, r2 = rem % 512;
  int lane = r2 >> 3, j = r2 & 7;
  int k = kb*32 + (lane >> 4)*8 + j;
  int col = cf*16 + (lane & 15);
  Bp[idx] = f2bf(W2[(size_t)k*C2 + col]);
}

// ---------------- batched scans ----------------
__global__ __launch_bounds__(BLK) void k_scan1_all(const int* __restrict__ ct,
    const int* __restrict__ cm, const int* __restrict__ cl,
    int2* __restrict__ bsum) {
  int bid = blockIdx.x;
  const int* cnt; int G, bo, cb;
  if (bid < NB_T)            { cnt = ct; G = G_TOPC; bo = BO_T; cb = bid; }
  else if (bid < NB_T+NB_M)  { cnt = cm; G = G_MEDC; bo = BO_M; cb = bid - NB_T; }
  else                       { cnt = cl; G = G_LOWC; bo = BO_L; cb = bid - NB_T - NB_M; }
  int base = cb * SCAN_CHUNK + threadIdx.x * SCAN_ITEMS;
  int so = 0, sp = 0;
  #pragma unroll
  for (int k = 0; k < SCAN_ITEMS; k++) {
    int j = base + k;
    if (j < G) { int c = cnt[j]; if (c > 0) { so++; sp += c; } }
  }
  __shared__ int sho[BLK], shp[BLK];
  sho[threadIdx.x] = so; shp[threadIdx.x] = sp; __syncthreads();
  for (int off = BLK/2; off > 0; off >>= 1) {
    if (threadIdx.x < off) {
      sho[threadIdx.x] += sho[threadIdx.x + off];
      shp[threadIdx.x] += shp[threadIdx.x + off];
    }
    __syncthreads();
  }
  if (threadIdx.x == 0) { int2 v; v.x = sho[0]; v.y = shp[0]; bsum[bo + cb] = v; }
}

// ---- scan2: 3 independent wave-level shuffle scans (no __syncthreads) ------
__global__ __launch_bounds__(192) void k_scan2_all(int2* __restrict__ bsum,
    int* __restrict__ Ut, int* __restrict__ Um, int* __restrict__ Ul) {
  int wv = threadIdx.x >> 6;
  int lane = threadIdx.x & 63;
  int off, nb; int* U;
  if (wv == 0)      { off = BO_T; nb = NB_T; U = Ut; }
  else if (wv == 1) { off = BO_M; nb = NB_M; U = Um; }
  else              { off = BO_L; nb = NB_L; U = Ul; }
  const int IPL = 9;                       // 64*9 = 576 >= 550
  int eo[IPL], ep[IPL];
  int accO = 0, accP = 0;
  #pragma unroll
  for (int k = 0; k < IPL; k++) {
    int idx = lane*IPL + k;
    int2 t = {0, 0};
    if (idx < nb) t = bsum[off + idx];
    eo[k] = accO; ep[k] = accP;            // within-lane exclusive prefix
    accO += t.x; accP += t.y;
  }
  int xo = accO, xp = accP;
  #pragma unroll
  for (int d = 1; d < 64; d <<= 1) {
    int to = __shfl_up(xo, d);
    int tp = __shfl_up(xp, d);
    if (lane >= d) { xo += to; xp += tp; }
  }
  int baseO = xo - accO, baseP = xp - accP;
  #pragma unroll
  for (int k = 0; k < IPL; k++) {
    int idx = lane*IPL + k;
    if (idx < nb) { int2 e; e.x = baseO + eo[k]; e.y = baseP + ep[k]; bsum[off + idx] = e; }
  }
  int tot = __shfl(xo, 63);
  if (lane == 0) *U = tot;
}

__global__ __launch_bounds__(BLK) void k_scan3_all(const int* __restrict__ ct,
    const int* __restrict__ cm, const int* __restrict__ cl,
    const int2* __restrict__ bsum,
    int* __restrict__ rkt, int* __restrict__ rkm, int* __restrict__ rkl,
    int* __restrict__ uqt, int* __restrict__ uqm, int* __restrict__ uql,
    int* __restrict__ wot, int* __restrict__ wom, int* __restrict__ wol) {
  int bid = blockIdx.x;
  const int* cnt; int G, bo, cb; int *rank, *uniq, *woff;
  if (bid < NB_T)           { cnt=ct; G=G_TOPC; bo=BO_T; cb=bid;            rank=rkt; uniq=uqt; woff=wot; }
  else if (bid < NB_T+NB_M) { cnt=cm; G=G_MEDC; bo=BO_M; cb=bid-NB_T;       rank=rkm; uniq=uqm; woff=wom; }
  else                      { cnt=cl; G=G_LOWC; bo=BO_L; cb=bid-NB_T-NB_M;  rank=rkl; uniq=uql; woff=wol; }
  int base = cb * SCAN_CHUNK + threadIdx.x * SCAN_ITEMS;
  int so = 0, sp = 0;
  #pragma unroll
  for (int k = 0; k < SCAN_ITEMS; k++) {
    int j = base + k;
    if (j < G) { int c = cnt[j]; if (c > 0) { so++; sp += c; } }
  }
  __shared__ int sho[BLK], shp[BLK];
  sho[threadIdx.x] = so; shp[threadIdx.x] = sp; __syncthreads();
  for (int off = 1; off < BLK; off <<= 1) {
    int ao = (threadIdx.x >= off) ? sho[threadIdx.x - off] : 0;
    int ap = (threadIdx.x >= off) ? shp[threadIdx.x - off] : 0;
    __syncthreads();
    sho[threadIdx.x] += ao; shp[threadIdx.x] += ap;
    __syncthreads();
  }
  int2 bb = bsum[bo + cb];
  int ro = bb.x + sho[threadIdx.x] - so;
  int po = bb.y + shp[threadIdx.x] - sp;
  for (int k = 0; k < SCAN_ITEMS; k++) {
    int j = base + k;
    if (j < G) {
      int c = cnt[j];
      if (c > 0) { rank[j] = ro; uniq[ro] = j; woff[ro] = po; ro++; po += c; }
    }
  }
}

// ------- fused: counting-sort scatter (3 scales) + parent child-lists -------
__global__ __launch_bounds__(BLK) void k_scatclist(const float* __restrict__ pts,
    const int* __restrict__ rkt, int* __restrict__ wot, float4* __restrict__ st, int* __restrict__ jt,
    const int* __restrict__ rkm, int* __restrict__ wom, float4* __restrict__ sm, int* __restrict__ jm,
    const int* __restrict__ rkl, int* __restrict__ wol, float4* __restrict__ sl, int* __restrict__ jl,
    const int* __restrict__ tuniq, const int* __restrict__ Utp,
    const int* __restrict__ cnt_m, const int* __restrict__ rank_m,
    int* __restrict__ clist_m, int* __restrict__ mcnt_m,
    const int* __restrict__ cnt_l, const int* __restrict__ rank_l,
    int* __restrict__ clist_l, int* __restrict__ mcnt_l) {
  int bid = blockIdx.x;
  if (bid < NPTS/BLK) {
    int i = bid * BLK + threadIdx.x;
    float b = pts[i*5+0], x = pts[i*5+1], y = pts[i*5+2], z = pts[i*5+3], it = pts[i*5+4];
    float4 p; p.x = x; p.y = y; p.z = z; p.w = it;
    {
      int r = rkt[lin3(b,x,y,z, 0.4f,0.4f,4.0f, 176,200,1)];
      int j = atomicAdd(&wot[r], 1); st[j] = p; jt[j] = r;
    }
    {
      int r = rkm[lin3(b,x,y,z, 0.2f,0.2f,2.0f, 352,400,2)];
      int j = atomicAdd(&wom[r], 1); sm[j] = p; jm[j] = r;
    }
    {
      int r = rkl[lin3(b,x,y,z, 0.1f,0.1f,1.0f, 704,800,4)];
      int j = atomicAdd(&wol[r], 1); sl[j] = p; jl[j] = r;
    }
    return;
  }
  int cb = bid - NPTS/BLK;
  const int *scnt, *srank; int *clist, *mcnt;
  int gx, gy, gz, f, rb;
  if (cb < NCL) { scnt=cnt_m; srank=rank_m; clist=clist_m; mcnt=mcnt_m;
                  gx=352; gy=400; gz=2; f=2; rb=cb; }
  else          { scnt=cnt_l; srank=rank_l; clist=clist_l; mcnt=mcnt_l;
                  gx=704; gy=800; gz=4; f=4; rb=cb-NCL; }
  int r = rb * BLK + threadIdx.x;
  if (r >= *Utp) return;
  int lin = tuniq[r];
  int x = lin % TGX; int t = lin / TGX;
  int y = t % TGY;   int b = t / TGY;   // TGZ == 1 so z == 0
  int m = 0;
  for (int cz = 0; cz < gz; cz++)
    for (int yy = y*f; yy < y*f + f; yy++)
      for (int xx = x*f; xx < x*f + f; xx++) {
        int cl = ((b*gz + cz)*gy + yy)*gx + xx;
        if (scnt[cl] > 0) clist[(size_t)r*64 + (m++)] = srank[cl];
      }
  mcnt[r] = m;
}

// ---------------- batched per-voxel xyz means ----------------
__global__ __launch_bounds__(BLK) void k_vox13(
    const float4* __restrict__ st, const int* __restrict__ uqt, const int* __restrict__ ct,
    const int* __restrict__ wot, const int* __restrict__ Ut, float4* __restrict__ vt,
    const float4* __restrict__ sm, const int* __restrict__ uqm, const int* __restrict__ cm,
    const int* __restrict__ wom, const int* __restrict__ Um, float4* __restrict__ vm,
    const float4* __restrict__ sl, const int* __restrict__ uql, const int* __restrict__ cl,
    const int* __restrict__ wol, const int* __restrict__ Ul, float4* __restrict__ vl) {
  int bid = blockIdx.x;
  const float4* srt; const int *uniq, *cnt, *woff, *Up; float4* vmean; int r;
  if (bid < NBVT)           { r = bid*BLK + threadIdx.x;           srt=st; uniq=uqt; cnt=ct; woff=wot; Up=Ut; vmean=vt; }
  else if (bid < NBVT+NBVM) { r = (bid-NBVT)*BLK + threadIdx.x;    srt=sm; uniq=uqm; cnt=cm; woff=wom; Up=Um; vmean=vm; }
  else                      { r = (bid-NBVT-NBVM)*BLK + threadIdx.x; srt=sl; uniq=uql; cnt=cl; woff=wol; Up=Ul; vmean=vl; }
  if (r >= *Up) return;
  int lin = uniq[r];
  int len = cnt[lin];
  int base = woff[r] - len;
  float sx = 0.f, sy = 0.f, sz = 0.f;
  for (int k = 0; k < len; k++) {
    float4 p = srt[base + k];
    sx += p.x; sy += p.y; sz += p.z;
  }
  float il = 1.0f / (float)len;
  float4 o; o.x = sx*il; o.y = sy*il; o.z = sz*il; o.w = il;
  vmean[r] = o;
}

// ------- f-moment partials (65 values: 10 means + 55 upper-tri products) ----
__global__ __launch_bounds__(BLK) void k_fmom_all(SP a, SP b, SP c) {
  int s = blockIdx.x >> 8;
  int blk = blockIdx.x & 255;
  SP sp = (s == 0) ? a : ((s == 1) ? b : c);
  float m[65];
  #pragma unroll
  for (int i = 0; i < 65; i++) m[i] = 0.f;
  #pragma unroll
  for (int k = 0; k < 4; k++) {
    int i = blk*1024 + k*BLK + threadIdx.x;
    float4 p = sp.srt[i];
    float4 vmn = sp.vm[sp.jr[i]];
    float f[10];
    build_f(p, vmn, sp.vx, sp.vy, sp.vz, sp.gx, sp.gy, sp.gz, f);
    int idx = 10;
    #pragma unroll
    for (int d = 0; d < 10; d++) {
      m[d] += f[d];
      #pragma unroll
      for (int e = d; e < 10; e++) {
        m[idx] = fmaf(f[d], f[e], m[idx]);
        idx++;
      }
    }
  }
  #pragma unroll
  for (int st = 1; st < 64; st <<= 1) {
    #pragma unroll
    for (int i = 0; i < 65; i++) m[i] += __shfl_xor(m[i], st);
  }
  __shared__ float ws[4][65];
  int wv = threadIdx.x >> 6;
  int lane = threadIdx.x & 63;
  if (lane == 0) {
    #pragma unroll
    for (int i = 0; i < 65; i++) ws[wv][i] = m[i];
  }
  __syncthreads();
  if (threadIdx.x < 65) {
    int t = threadIdx.x;
    sp.part1[(size_t)blk*65 + t] = ws[0][t] + ws[1][t] + ws[2][t] + ws[3][t];
  }
}

// ---- reduce f-moments -> BN1 coef via mu = E[f]^T w, E[y^2] = w^T M w ------
__global__ __launch_bounds__(BLK) void k_mcoef_all(SP a, SP b, SP c) {
  SP sp = (blockIdx.x == 0) ? a : ((blockIdx.x == 1) ? b : c);
  const int C1 = sp.C1;
  __shared__ float M[65];
  int t = threadIdx.x;
  if (t < 65) {
    float s = 0.f;
    #pragma unroll 8
    for (int bk = 0; bk < ST1BLKS; bk++) s += sp.part1[(size_t)bk*65 + t];
    M[t] = s * (1.0f / NPTS);
  }
  __syncthreads();
  if (t < C1) {
    float wv[10];
    #pragma unroll
    for (int d = 0; d < 10; d++) wv[d] = sp.W1[d*C1 + t];
    float mu = 0.f;
    #pragma unroll
    for (int d = 0; d < 10; d++) mu = fmaf(M[d], wv[d], mu);
    float ey2 = 0.f;
    int idx = 10;
    #pragma unroll
    for (int d = 0; d < 10; d++) {
      #pragma unroll
      for (int e = d; e < 10; e++) {
        float c2 = M[idx] * wv[d] * wv[e];
        ey2 += (e == d) ? c2 : 2.0f * c2;
        idx++;
      }
    }
    float var = ey2 - mu*mu;
    float sc  = sp.g1[t] * (1.0f / sqrtf(var + 1e-3f));
    sp.coef1[t]      = sc;
    sp.coef1[C1 + t] = fmaf(-mu, sc, sp.b1[t]);
  }
}

// ---- layer-2 stats partials reduce -> BN2 coef -----------------------------
__device__ __forceinline__ void partcoef_body(const float* part, int NB, int C,
    int ch, const float* g, const float* b, float* coef) {
  float s = 0.f, q = 0.f;
  for (int bk = threadIdx.x; bk < NB; bk += BLK) {
    s += part[(size_t)bk*2*C + ch];
    q += part[(size_t)bk*2*C + C + ch];
  }
  __shared__ float ss[BLK], sq[BLK];
  ss[threadIdx.x] = s; sq[threadIdx.x] = q; __syncthreads();
  for (int off = BLK/2; off > 0; off >>= 1) {
    if (threadIdx.x < off) {
      ss[threadIdx.x] += ss[threadIdx.x + off];
      sq[threadIdx.x] += sq[threadIdx.x + off];
    }
    __syncthreads();
  }
  if (threadIdx.x == 0) {
    float mu  = ss[0] * (1.0f / NPTS);
    float var = sq[0] * (1.0f / NPTS) - mu*mu;
    float sc  = g[ch] * (1.0f / sqrtf(var + 1e-3f));
    coef[ch]     = sc;
    coef[C + ch] = fmaf(-mu, sc, b[ch]);
  }
}

__global__ __launch_bounds__(BLK) void k_partcoef2_all(SP a, SP b, SP c) {
  int bid = blockIdx.x; SP sp; int ch;
  if (bid < 128)      { sp = a; ch = bid; }
  else if (bid < 192) { sp = b; ch = bid - 128; }
  else                { sp = c; ch = bid - 192; }
  if (ch >= 2*sp.C1) return;
  partcoef_body(sp.part2, Y2B2, 2*sp.C1, ch, sp.g2, sp.b2, sp.coef2);
}

// ---- layer-1 voxel means of BN+ReLU(y1), 8 channels/thread, bf16 out -------
__global__ __launch_bounds__(BLK) void k_hsegT_all(SP a, SP b, SP c) {
  int bid = blockIdx.x; SP sp; int rb;
  if (bid < NHT2)           { sp = a; rb = bid; }
  else if (bid < NHT2+NHM2) { sp = b; rb = bid - NHT2; }
  else                      { sp = c; rb = bid - NHT2 - NHM2; }
  const int C1 = sp.C1;
  const int qsh = (C1 == 64) ? 3 : 2;      // threads per voxel = C1/8
  __shared__ float w[640];
  __shared__ float sc[64], sb[64];
  for (int t = threadIdx.x; t < 10*C1; t += BLK) w[t] = sp.W1[t];
  for (int t = threadIdx.x; t < C1; t += BLK) { sc[t] = sp.coef1[t]; sb[t] = sp.coef1[C1 + t]; }
  __syncthreads();
  int tid = rb * BLK + threadIdx.x;
  int r = tid >> qsh;
  int q = tid & ((1 << qsh) - 1);
  if (r >= *sp.U) return;
  int lin = sp.uniq[r];
  int len = sp.cnt[lin];
  int base = sp.woff[r] - len;
  float4 vmn = sp.vm[r];
  int c0 = q * 8;
  float s[8], o[8], acc[8];
  #pragma unroll
  for (int e = 0; e < 8; e++) { s[e] = sc[c0+e]; o[e] = sb[c0+e]; acc[e] = 0.f; }
  for (int k = 0; k < len; k++) {
    float4 p = sp.srt[base + k];
    float f[10];
    build_f(p, vmn, sp.vx, sp.vy, sp.vz, sp.gx, sp.gy, sp.gz, f);
    float y[8] = {0,0,0,0,0,0,0,0};
    #pragma unroll
    for (int d = 0; d < 10; d++) {
      float fv = f[d];
      const float* wr = &w[d*C1 + c0];
      #pragma unroll
      for (int e = 0; e < 8; e++) y[e] = fmaf(fv, wr[e], y[e]);
    }
    #pragma unroll
    for (int e = 0; e < 8; e++) acc[e] += fmaxf(fmaf(y[e], s[e], o[e]), 0.f);
  }
  float il = 1.0f / (float)len;
  #pragma unroll
  for (int e = 0; e < 8; e++)
    sp.segt[(size_t)(c0+e)*sp.segstride + r] = f2bf(acc[e]*il);
}

// ------- layer 2 as MFMA bf16 GEMM (64-row tiles); fused column stats -------
template<int C1>
__device__ __forceinline__ void y2m_body(const SP& sp,
    const unsigned short* __restrict__ Bpk, int blk, unsigned short* Alds) {
  constexpr int K   = 2*C1;
  constexpr int C2  = 2*C1;
  constexpr int MT  = 64;
  constexpr int NKB = K / 32;          // 4 (top), 2 (med/low)
  constexpr int NCF = C2 / 16;         // 8 (top), 4 (med/low)
  constexpr int RB  = K * 2;           // row bytes in Alds
  const int tid  = threadIdx.x;
  const int base = blk * MT;

  // ---- stage A tile (bf16, XOR-swizzled): 4 threads/row, K/4 channels each
  {
    const int jst = tid & 63;
    const int qst = tid >> 6;          // wave id == channel-quarter (wave-uniform)
    int jr = sp.jr[base + jst];
    float4 p = sp.srt[base + jst];
    float4 vmn = sp.vm[jr];
    float fs[10];
    build_f(p, vmn, sp.vx, sp.vy, sp.vz, sp.gx, sp.gy, sp.gz, fs);
    const int k_lo = qst * (K/4);
    #pragma unroll
    for (int kk = 0; kk < K/8; kk++) {
      int k0 = k_lo + kk*2;
      unsigned u;
      if (k0 < C1) {
        float y0 = 0.f, y1v = 0.f;
        #pragma unroll
        for (int d = 0; d < 10; d++) {
          y0  = fmaf(fs[d], sp.W1[d*C1 + k0],     y0);
          y1v = fmaf(fs[d], sp.W1[d*C1 + k0 + 1], y1v);
        }
        float v0 = fmaxf(fmaf(y0,  sp.coef1[k0],   sp.coef1[C1 + k0]),   0.f);
        float v1 = fmaxf(fmaf(y1v, sp.coef1[k0+1], sp.coef1[C1 + k0+1]), 0.f);
        u = (unsigned)f2bf(v0) | ((unsigned)f2bf(v1) << 16);
      } else {
        unsigned s0 = sp.segt[(size_t)(k0     - C1)*sp.segstride + jr];
        unsigned s1 = sp.segt[(size_t)(k0 + 1 - C1)*sp.segstride + jr];
        u = s0 | (s1 << 16);
      }
      int g  = k0 >> 3;
      int gp = g ^ (jst & 7);
      *(unsigned*)((char*)Alds + (size_t)jst*RB + gp*16 + (k0 & 7)*2) = u;
    }
  }
  __syncthreads();

  // ---- MFMA main loop: wave w owns rows [w*16, w*16+16) ----
  const int w    = tid >> 6;
  const int l    = tid & 63;
  const int rowf = l & 15;
  const int kg   = l >> 4;
  const int row  = w*16 + rowf;
  f32x4 acc[NCF];
  #pragma unroll
  for (int cf = 0; cf < NCF; cf++) acc[cf] = (f32x4){0.f, 0.f, 0.f, 0.f};
  #pragma unroll
  for (int kb = 0; kb < NKB; kb++) {
    int g  = kb*4 + kg;
    int gp = g ^ (row & 7);
    bf16x8 a = *(const bf16x8*)((const char*)Alds + (size_t)row*RB + gp*16);
    const bf16x8* bfr = (const bf16x8*)Bpk + (size_t)(kb*NCF)*64 + l;
    #pragma unroll
    for (int cf = 0; cf < NCF; cf++) {
      bf16x8 b = bfr[cf*64];
      acc[cf] = __builtin_amdgcn_mfma_f32_16x16x32_bf16(a, b, acc[cf], 0, 0, 0);
    }
  }

  // ---- fused column sum/sumsq partials from fp32 acc (reuse Alds) ----
  __syncthreads();
  float* red = (float*)Alds;           // [32][C2] floats == Alds byte size
  #pragma unroll
  for (int cf = 0; cf < NCF; cf++) {
    f32x4 v = acc[cf];
    float sv = v.x + v.y + v.z + v.w;
    float qv = v.x*v.x + v.y*v.y + v.z*v.z + v.w*v.w;
    red[(w*4 + kg)*C2 + cf*16 + rowf]        = sv;
    red[(16 + w*4 + kg)*C2 + cf*16 + rowf]   = qv;
  }
  __syncthreads();
  if (tid < C2) {
    float sv = 0.f, qv = 0.f;
    #pragma unroll 4
    for (int i = 0; i < 16; i++) {
      sv += red[i*C2 + tid];
      qv += red[(16 + i)*C2 + tid];
    }
    sp.part2[(size_t)blk*2*C2 + tid]      = sv;
    sp.part2[(size_t)blk*2*C2 + C2 + tid] = qv;
  }
  __syncthreads();

  // ---- D -> LDS (bf16, row-major) -> coalesced global store ----
  unsigned short* D = Alds;
  #pragma unroll
  for (int cf = 0; cf < NCF; cf++) {
    #pragma unroll
    for (int rg = 0; rg < 4; rg++) {
      int rr = w*16 + kg*4 + rg;       // C/D: col=lane&15, row=(lane>>4)*4+reg
      D[rr*C2 + cf*16 + rowf] = f2bf(acc[cf][rg]);
    }
  }
  __syncthreads();
  for (int it = tid; it < MT*C2/8; it += BLK) {
    int r = (it*8) / C2;
    int c = (it*8) % C2;
    uint4 v = *(const uint4*)&D[it*8];
    *(uint4*)&sp.Y2[(size_t)(base + r)*C2 + c] = v;
  }
}

__global__ __launch_bounds__(BLK) void k_y2m_all(SP a, SP b, SP c,
    const unsigned short* __restrict__ Bt, const unsigned short* __restrict__ Bm,
    const unsigned short* __restrict__ Bl) {
  __shared__ unsigned short Alds[64*128];   // 16 KB (med/low use half)
  int bid = blockIdx.x;
  if (bid < Y2B2)        y2m_body<64>(a, Bt, bid, Alds);
  else if (bid < 2*Y2B2) y2m_body<32>(b, Bm, bid - Y2B2, Alds);
  else                   y2m_body<32>(c, Bl, bid - 2*Y2B2, Alds);
}

// -------- layer-2 BN+ReLU + voxel mean (bf16 Y2, 8 channels/thread) ---------
__global__ __launch_bounds__(BLK) void k_hseg2_all(SP a, SP b, SP c) {
  int bid = blockIdx.x; SP sp; int rb;
  if (bid < NJT2)           { sp = a; rb = bid; }
  else if (bid < NJT2+NJM2) { sp = b; rb = bid - NJT2; }
  else                      { sp = c; rb = bid - NJT2 - NJM2; }
  const int C = 2*sp.C1;
  const int qsh = (C == 128) ? 4 : 3;      // threads per voxel = C/8
  __shared__ float sc[128], sb[128];
  for (int t = threadIdx.x; t < C; t += BLK) { sc[t] = sp.coef2[t]; sb[t] = sp.coef2[C + t]; }
  __syncthreads();
  int tid = rb * BLK + threadIdx.x;
  int r = tid >> qsh;
  int q = tid & ((1 << qsh) - 1);
  if (r >= *sp.U) return;
  int lin = sp.uniq[r];
  int len = sp.cnt[lin];
  int base = sp.woff[r] - len;
  int c0 = q * 8;
  float s[8], o[8], acc[8];
  #pragma unroll
  for (int e = 0; e < 8; e++) { s[e] = sc[c0+e]; o[e] = sb[c0+e]; acc[e] = 0.f; }
  const unsigned short* Yh = sp.Y2;
  for (int k = 0; k < len; k++) {
    uint4 hv = *(const uint4*)&Yh[(size_t)(base + k)*C + c0];
    unsigned uu[4] = {hv.x, hv.y, hv.z, hv.w};
    #pragma unroll
    for (int j = 0; j < 4; j++) {
      float lo = __uint_as_float(uu[j] << 16);
      float hi = __uint_as_float(uu[j] & 0xFFFF0000u);
      acc[2*j+0] += fmaxf(fmaf(lo, s[2*j+0], o[2*j+0]), 0.f);
      acc[2*j+1] += fmaxf(fmaf(hi, s[2*j+1], o[2*j+1]), 0.f);
    }
  }
  float il = 1.0f / (float)len;
  float4 o0 = {acc[0]*il, acc[1]*il, acc[2]*il, acc[3]*il};
  float4 o1 = {acc[4]*il, acc[5]*il, acc[6]*il, acc[7]*il};
  *(float4*)&sp.hout[(size_t)r*C + c0]     = o0;
  *(float4*)&sp.hout[(size_t)r*C + c0 + 4] = o1;
}

// ---- fused: merge means into mg (r<U) + tail zero + coors ------------------
__global__ __launch_bounds__(BLK) void k_mergefin(
    const float* __restrict__ vox_m, const int* __restrict__ clist_m,
    const int* __restrict__ mcnt_m,
    const float* __restrict__ vox_l, const int* __restrict__ clist_l,
    const int* __restrict__ mcnt_l,
    const int* __restrict__ uniq, const int* __restrict__ Up,
    float* __restrict__ vf, float* __restrict__ mg, float* __restrict__ coors) {
  int bid = blockIdx.x;
  if (bid < 2*NMG) {
    const float* vox; const int *clist, *mcnt; int half, rb;
    if (bid < NMG) { vox=vox_m; clist=clist_m; mcnt=mcnt_m; half=0; rb=bid; }
    else           { vox=vox_l; clist=clist_l; mcnt=mcnt_l; half=64; rb=bid-NMG; }
    int idx = rb * BLK + threadIdx.x;
    int r = idx >> 4;
    int q = idx & 15;
    if (r >= *Up) return;
    int m = mcnt[r];
    float a0=0.f, a1=0.f, a2=0.f, a3=0.f;
    for (int t = 0; t < m; t++) {
      int cr = clist[(size_t)r*64 + t];
      float4 v = *(const float4*)&vox[(size_t)cr*64 + q*4];
      a0 += v.x; a1 += v.y; a2 += v.z; a3 += v.w;
    }
    float inv = 1.0f / (float)max(m, 1);
    float4 o = {a0*inv, a1*inv, a2*inv, a3*inv};
    *(float4*)&mg[(size_t)r*128 + half + q*4] = o;
    return;
  }
  int idx = (bid - 2*NMG) * BLK + threadIdx.x;
  int r = idx >> 5;
  int q = idx & 31;
  if (r >= NPTS) return;
  int U = *Up;
  if (r >= U) {
    float4 z = {0.f, 0.f, 0.f, 0.f};
    *(float4*)&mg[(size_t)r*128 + q*4] = z;
    *(float4*)&vf[(size_t)r*128 + q*4] = z;
  }
  if (q == 0) {
    float4 co;
    if (r < U) {
      int lin = uniq[r];
      int x = lin % TGX; int t = lin / TGX;
      int y = t % TGY;   t /= TGY;
      int z = t % TGZ;   int b = t / TGZ;
      co.x = (float)b; co.y = (float)z; co.z = (float)y; co.w = (float)x;
    } else {
      co.x = -1.f; co.y = -1.f; co.z = -1.f; co.w = -1.f;
    }
    *(float4*)&coors[(size_t)r*4] = co;
  }
}

extern "C" void kernel_launch(void* const* d_in, const int* in_sizes, int n_in,
                              void* d_out, int out_size, void* d_ws, size_t ws_size,
                              hipStream_t stream) {
  const float* pts = (const float*)d_in[0];

  float* out = (float*)d_out;
  float* vf = out;                              // N x 128 (final vf)
  float* mg = out + (size_t)NPTS * 128;         // N x 128 (merged)
  float* co = out + (size_t)NPTS * 256;         // N x 4   (coors)

  char* w = (char*)d_ws;
  size_t off = 0;
  auto alloc = [&](size_t bytes) -> void* {
    void* p = w + off;
    off = (off + bytes + 1023) & ~(size_t)1023;
    return p;
  };
  int*    cnt_t   = (int*)alloc(((size_t)G_TOPC + G_MEDC + G_LOWC) * 4);
  int*    cnt_m   = cnt_t + G_TOPC;
  int*    cnt_l   = cnt_t + G_TOPC + G_MEDC;
  int*    rank_t  = (int*)alloc((size_t)G_TOPC * 4);
  int*    rank_m  = (int*)alloc((size_t)G_MEDC * 4);
  int*    rank_l  = (int*)alloc((size_t)G_LOWC * 4);
  int*    uniq_t  = (int*)alloc((size_t)G_TOPC * 4);
  int*    uniq_m  = (int*)alloc((size_t)NPTS * 4);
  int*    uniq_l  = (int*)alloc((size_t)NPTS * 4);
  int*    woff_t  = (int*)alloc((size_t)G_TOPC * 4);
  int*    woff_m  = (int*)alloc((size_t)NPTS * 4);
  int*    woff_l  = (int*)alloc((size_t)NPTS * 4);
  float4* srt_t   = (float4*)alloc((size_t)NPTS * 16);
  float4* srt_m   = (float4*)alloc((size_t)NPTS * 16);
  float4* srt_l   = (float4*)alloc((size_t)NPTS * 16);
  int*    jr_t    = (int*)alloc((size_t)NPTS * 4);
  int*    jr_m    = (int*)alloc((size_t)NPTS * 4);
  int*    jr_l    = (int*)alloc((size_t)NPTS * 4);
  float4* vm_t    = (float4*)alloc((size_t)G_TOPC * 16);
  float4* vm_m    = (float4*)alloc((size_t)NPTS * 16);
  float4* vm_l    = (float4*)alloc((size_t)NPTS * 16);
  unsigned short* segt_t = (unsigned short*)alloc((size_t)G_TOPC * 64 * 2);
  unsigned short* segt_m = (unsigned short*)alloc((size_t)NPTS * 32 * 2);
  unsigned short* segt_l = (unsigned short*)alloc((size_t)NPTS * 32 * 2);
  float*  vox_m   = (float*)alloc((size_t)NPTS * 64 * 4);
  float*  vox_l   = (float*)alloc((size_t)NPTS * 64 * 4);
  unsigned short* Y2h_t = (unsigned short*)alloc((size_t)NPTS * 128 * 2);
  unsigned short* Y2h_m = (unsigned short*)alloc((size_t)NPTS * 64 * 2);
  unsigned short* Y2h_l = (unsigned short*)alloc((size_t)NPTS * 64 * 2);
  unsigned short* Bpk_t = (unsigned short*)alloc(16384 * 2);
  unsigned short* Bpk_m = (unsigned short*)alloc(4096 * 2);
  unsigned short* Bpk_l = (unsigned short*)alloc(4096 * 2);
  int*    clist_m = (int*)alloc((size_t)G_TOPC * 64 * 4);
  int*    clist_l = (int*)alloc((size_t)G_TOPC * 64 * 4);
  int*    mcnt_m  = (int*)alloc((size_t)G_TOPC * 4);
  int*    mcnt_l  = (int*)alloc((size_t)G_TOPC * 4);
  float*  part1_t = (float*)alloc((size_t)ST1BLKS * 128 * 4);
  float*  part1_m = (float*)alloc((size_t)ST1BLKS * 128 * 4);
  float*  part1_l = (float*)alloc((size_t)ST1BLKS * 128 * 4);
  float*  part2_t = (float*)alloc((size_t)Y2B2 * 256 * 4);
  float*  part2_m = (float*)alloc((size_t)Y2B2 * 128 * 4);
  float*  part2_l = (float*)alloc((size_t)Y2B2 * 128 * 4);
  float*  coef    = (float*)alloc(6 * 256 * 4);
  int2*   bsum    = (int2*)alloc(1024 * 8);
  int*    Ut      = (int*)alloc(64);
  int*    Um      = (int*)alloc(64);
  int*    Ul      = (int*)alloc(64);
  (void)in_sizes; (void)n_in; (void)out_size; (void)ws_size;

  auto mkSP = [&](int scaleIdx) -> SP {
    SP s{};
    if (scaleIdx == 0) {
      s.srt = srt_t; s.jr = jr_t; s.vm = vm_t;
      s.W1 = (const float*)d_in[2];  s.g1 = (const float*)d_in[3];
      s.b1 = (const float*)d_in[4];  s.W2 = (const float*)d_in[5];
      s.g2 = (const float*)d_in[6];  s.b2 = (const float*)d_in[7];
      s.cnt = cnt_t; s.uniq = uniq_t; s.woff = woff_t; s.U = Ut;
      s.segt = segt_t; s.part1 = part1_t; s.part2 = part2_t;
      s.coef1 = coef + 0*256; s.coef2 = coef + 1*256;
      s.Y2 = Y2h_t; s.hout = vf;
      s.C1 = 64; s.segstride = G_TOPC;
      s.gx = 176; s.gy = 200; s.gz = 1; s.vx = 0.4f; s.vy = 0.4f; s.vz = 4.0f;
    } else if (scaleIdx == 1) {
      s.srt = srt_m; s.jr = jr_m; s.vm = vm_m;
      s.W1 = (const float*)d_in[8];  s.g1 = (const float*)d_in[9];
      s.b1 = (const float*)d_in[10]; s.W2 = (const float*)d_in[11];
      s.g2 = (const float*)d_in[12]; s.b2 = (const float*)d_in[13];
      s.cnt = cnt_m; s.uniq = uniq_m; s.woff = woff_m; s.U = Um;
      s.segt = segt_m; s.part1 = part1_m; s.part2 = part2_m;
      s.coef1 = coef + 2*256; s.coef2 = coef + 3*256;
      s.Y2 = Y2h_m; s.hout = vox_m;
      s.C1 = 32; s.segstride = NPTS;
      s.gx = 352; s.gy = 400; s.gz = 2; s.vx = 0.2f; s.vy = 0.2f; s.vz = 2.0f;
    } else {
      s.srt = srt_l; s.jr = jr_l; s.vm = vm_l;
      s.W1 = (const float*)d_in[14]; s.g1 = (const float*)d_in[15];
      s.b1 = (const float*)d_in[16]; s.W2 = (const float*)d_in[17];
      s.g2 = (const float*)d_in[18]; s.b2 = (const float*)d_in[19];
      s.cnt = cnt_l; s.uniq = uniq_l; s.woff = woff_l; s.U = Ul;
      s.segt = segt_l; s.part1 = part1_l; s.part2 = part2_l;
      s.coef1 = coef + 4*256; s.coef2 = coef + 5*256;
      s.Y2 = Y2h_l; s.hout = vox_l;
      s.C1 = 32; s.segstride = NPTS;
      s.gx = 704; s.gy = 800; s.gz = 4; s.vx = 0.1f; s.vy = 0.1f; s.vz = 1.0f;
    }
    return s;
  };
  SP spT = mkSP(0), spM = mkSP(1), spL = mkSP(2);

  // ---- batched voxelization front-end ----
  (void)hipMemsetAsync(cnt_t, 0, ((size_t)G_TOPC + G_MEDC + G_LOWC) * 4, stream);
  k_count3pack<<<NPTS/BLK + 96, BLK, 0, stream>>>(pts, cnt_t, cnt_m, cnt_l,
      (const float*)d_in[5], Bpk_t, (const float*)d_in[11], Bpk_m,
      (const float*)d_in[17], Bpk_l);
  k_scan1_all<<<NB_T + NB_M + NB_L, BLK, 0, stream>>>(cnt_t, cnt_m, cnt_l, bsum);
  k_scan2_all<<<1, 192, 0, stream>>>(bsum, Ut, Um, Ul);
  k_scan3_all<<<NB_T + NB_M + NB_L, BLK, 0, stream>>>(cnt_t, cnt_m, cnt_l, bsum,
      rank_t, rank_m, rank_l, uniq_t, uniq_m, uniq_l, woff_t, woff_m, woff_l);
  k_scatclist<<<NPTS/BLK + 2*NCL, BLK, 0, stream>>>(pts,
      rank_t, woff_t, srt_t, jr_t,
      rank_m, woff_m, srt_m, jr_m,
      rank_l, woff_l, srt_l, jr_l,
      uniq_t, Ut, cnt_m, rank_m, clist_m, mcnt_m, cnt_l, rank_l, clist_l, mcnt_l);
  k_vox13<<<NBVT + NBVM + NBVL, BLK, 0, stream>>>(
      srt_t, uniq_t, cnt_t, woff_t, Ut, vm_t,
      srt_m, uniq_m, cnt_m, woff_m, Um, vm_m,
      srt_l, uniq_l, cnt_l, woff_l, Ul, vm_l);

  // ---- batched VFE pipeline (all scales per stage) ----
  k_fmom_all<<<3*ST1BLKS, BLK, 0, stream>>>(spT, spM, spL);
  k_mcoef_all<<<3, BLK, 0, stream>>>(spT, spM, spL);
  k_hsegT_all<<<NHT2 + 2*NHM2, BLK, 0, stream>>>(spT, spM, spL);
  k_y2m_all<<<3*Y2B2, BLK, 0, stream>>>(spT, spM, spL, Bpk_t, Bpk_m, Bpk_l);
  k_partcoef2_all<<<256, BLK, 0, stream>>>(spT, spM, spL);
  k_hseg2_all<<<NJT2 + 2*NJM2, BLK, 0, stream>>>(spT, spM, spL);

  // ---- merges + final outputs (one kernel) ----
  k_mergefin<<<2*NMG + FINB, BLK, 0, stream>>>(vox_m, clist_m, mcnt_m,
      vox_l, clist_l, mcnt_l, uniq_t, Ut, vf, mg, co);
}